// Round 10
// baseline (391.100 us; speedup 1.0000x reference)
//
#include <hip/hip_runtime.h>
#include <hip/hip_bf16.h>
#include <math.h>

typedef __bf16 bf16;
typedef bf16 bf16x4 __attribute__((ext_vector_type(4)));
typedef bf16 bf16x8 __attribute__((ext_vector_type(8)));
typedef float f32x4 __attribute__((ext_vector_type(4)));

#define B_ 4
#define S_ 2048
#define HID_ 1024
#define NH_ 16
#define HD_ 64
#define LTS 72   // padded LDS tile stride

// async global->LDS, 16B per lane. LDS dest must be wave-uniform base + lane*16.
__device__ __forceinline__ void async16(const bf16* g, bf16* l) {
  __builtin_amdgcn_global_load_lds(
      (const __attribute__((address_space(1))) void*)g,
      (__attribute__((address_space(3))) void*)l, 16, 0, 0);
}

#define MM16(A, B, C) C = __builtin_amdgcn_mfma_f32_16x16x32_bf16(A, B, C, 0, 0, 0)

// pack two f32 -> u32 of 2 bf16 (no builtin on gfx950; T12 recipe)
__device__ __forceinline__ unsigned cvtpk(float lo, float hi) {
  unsigned r;
  asm("v_cvt_pk_bf16_f32 %0, %1, %2" : "=v"(r) : "v"(lo), "v"(hi));
  return r;
}

// ---------------- fp32 -> bf16 convert
__global__ void cvt_kernel(const float* __restrict__ src, bf16* __restrict__ dst, int n4) {
  int i = blockIdx.x * 256 + threadIdx.x;
  if (i < n4) {
    float4 v = ((const float4*)src)[i];
    bf16x4 o;
    o[0] = (bf16)v.x; o[1] = (bf16)v.y; o[2] = (bf16)v.z; o[3] = (bf16)v.w;
    ((bf16x4*)dst)[i] = o;
  }
}

// K-loop body shared by qkv/proj: named accs, frag loads, 16 MFMAs.
#define DECL_ACC \
  f32x4 a00 = {}, a01 = {}, a02 = {}, a03 = {}; \
  f32x4 a10 = {}, a11 = {}, a12 = {}, a13 = {}; \
  f32x4 a20 = {}, a21 = {}, a22 = {}, a23 = {}; \
  f32x4 a30 = {}, a31 = {}, a32 = {}, a33 = {};

#define KLOOP_FRAGS_MFMA \
    bf16x8 af0 = *(const bf16x8*)(lA + (wm + 0 * 16 + l16) * 32 + quad * 8); \
    bf16x8 af1 = *(const bf16x8*)(lA + (wm + 1 * 16 + l16) * 32 + quad * 8); \
    bf16x8 af2 = *(const bf16x8*)(lA + (wm + 2 * 16 + l16) * 32 + quad * 8); \
    bf16x8 af3 = *(const bf16x8*)(lA + (wm + 3 * 16 + l16) * 32 + quad * 8); \
    bf16x8 bg0 = *(const bf16x8*)(lB + (wn + 0 * 16 + l16) * 32 + quad * 8); \
    bf16x8 bg1 = *(const bf16x8*)(lB + (wn + 1 * 16 + l16) * 32 + quad * 8); \
    bf16x8 bg2 = *(const bf16x8*)(lB + (wn + 2 * 16 + l16) * 32 + quad * 8); \
    bf16x8 bg3 = *(const bf16x8*)(lB + (wn + 3 * 16 + l16) * 32 + quad * 8); \
    MM16(af0, bg0, a00); MM16(af0, bg1, a01); MM16(af0, bg2, a02); MM16(af0, bg3, a03); \
    MM16(af1, bg0, a10); MM16(af1, bg1, a11); MM16(af1, bg2, a12); MM16(af1, bg3, a13); \
    MM16(af2, bg0, a20); MM16(af2, bg1, a21); MM16(af2, bg2, a22); MM16(af2, bg3, a23); \
    MM16(af3, bg0, a30); MM16(af3, bg1, a31); MM16(af3, bg2, a32); MM16(af3, bg3, a33);

// RoPE epilogue per (i, r) — fast trig (range ~2048 rad: __cosf err ~1e-4 << bf16 eps)
#define ROPE_R(i, r, C0, C1, C2, C3) { \
  const int mloc = (i) * 16 + quad * 4 + (r); \
  const float p = (float)pos[mbase + mloc]; \
  const float aa0 = p * invf0, aa1 = p * invf1; \
  const float c0 = __cosf(aa0), sn0 = __sinf(aa0); \
  const float c1 = __cosf(aa1), sn1 = __sinf(aa1); \
  myT[mloc * LTS + l16]      = (bf16)((C0[r] * c0 - C2[r] * sn0) * scl); \
  myT[mloc * LTS + 32 + l16] = (bf16)((C2[r] * c0 + C0[r] * sn0) * scl); \
  myT[mloc * LTS + 16 + l16] = (bf16)((C1[r] * c1 - C3[r] * sn1) * scl); \
  myT[mloc * LTS + 48 + l16] = (bf16)((C3[r] * c1 + C1[r] * sn1) * scl); }
#define ROPE_I(i, C0, C1, C2, C3) \
  ROPE_R(i, 0, C0, C1, C2, C3) ROPE_R(i, 1, C0, C1, C2, C3) \
  ROPE_R(i, 2, C0, C1, C2, C3) ROPE_R(i, 3, C0, C1, C2, C3)

#define VW(i, j, C) { \
  bf16x4 o; o[0] = (bf16)C[0]; o[1] = (bf16)C[1]; o[2] = (bf16)C[2]; o[3] = (bf16)C[3]; \
  *(bf16x4*)(myT + ((j) * 16 + l16) * LTS + (i) * 16 + quad * 4) = o; }

// ---------------- QKV GEMM: Y = Xb @ Wb^T, fused RoPE. (round-9 version)
__global__ void qkv_gemm(
    const bf16* __restrict__ X, const bf16* __restrict__ Wq,
    const bf16* __restrict__ Wk, const bf16* __restrict__ Wv,
    const int* __restrict__ pos,
    bf16* __restrict__ Q, bf16* __restrict__ Ko, bf16* __restrict__ Vt) {
  const int f = blockIdx.x;
  const int orig = (f & 7) * 192 + (f >> 3);
  const int m_idx = orig / 24, nz = orig % 24;
  const int z = nz % 3;
  const bf16* W = (z == 0) ? Wq : (z == 1) ? Wk : Wv;
  const int m0 = m_idx * 128;
  const int n0 = (nz / 3) * 128;
  __shared__ __align__(16) bf16 lA[128 * 32];
  __shared__ __align__(16) bf16 lB[128 * 32];
  __shared__ __align__(16) bf16 lT[2][64 * LTS];  // 2-phase epilogue buffer
  const int tid = threadIdx.x;
  const int lane = tid & 63, w = tid >> 6;
  const int wm = (w >> 1) * 64, wn = (w & 1) * 64;
  const int quad = lane >> 4, l16 = lane & 15;

  DECL_ACC

  const int qa = tid, qb = tid + 256;
  const int ra = qa >> 2, ca = (qa & 3) * 8;
  const int rb = qb >> 2, cb = (qb & 3) * 8;

  for (int k0 = 0; k0 < 1024; k0 += 32) {
    async16(X + (size_t)(m0 + ra) * 1024 + k0 + ca, lA + qa * 8);
    async16(X + (size_t)(m0 + rb) * 1024 + k0 + cb, lA + qb * 8);
    async16(W + (size_t)(n0 + ra) * 1024 + k0 + ca, lB + qa * 8);
    async16(W + (size_t)(n0 + rb) * 1024 + k0 + cb, lB + qb * 8);
    __syncthreads();
    KLOOP_FRAGS_MFMA
    __syncthreads();
  }

  const int h = (n0 + wn) >> 6;
  const int mbase = m0 + wm;
  const int b = mbase >> 11, s0 = mbase & 2047;
  bf16* myT = lT[w & 1];

  auto epilogue = [&]() {
    if (z <= 1) {
      const float scl = (z == 0) ? 0.125f : 1.0f;
      const float invf0 = __expf(-0.28782313662425572f * (float)l16);   // ln(1e4)/32
      const float invf1 = __expf(-0.28782313662425572f * (float)(16 + l16));
      ROPE_I(0, a00, a01, a02, a03)
      ROPE_I(1, a10, a11, a12, a13)
      ROPE_I(2, a20, a21, a22, a23)
      ROPE_I(3, a30, a31, a32, a33)
      asm volatile("s_waitcnt lgkmcnt(0)" ::: "memory");
      bf16* dst = (z == 0) ? Q : Ko;
      const int rr = lane >> 3, cc = lane & 7;
#pragma unroll
      for (int it = 0; it < 8; it++) {
        int mloc = it * 8 + rr;
        bf16x8 v = *(const bf16x8*)(myT + mloc * LTS + cc * 8);
        *(bf16x8*)(dst + (((size_t)b * NH_ + h) * S_ + s0 + mloc) * HD_ + cc * 8) = v;
      }
    } else {
      VW(0, 0, a00) VW(0, 1, a01) VW(0, 2, a02) VW(0, 3, a03)
      VW(1, 0, a10) VW(1, 1, a11) VW(1, 2, a12) VW(1, 3, a13)
      VW(2, 0, a20) VW(2, 1, a21) VW(2, 2, a22) VW(2, 3, a23)
      VW(3, 0, a30) VW(3, 1, a31) VW(3, 2, a32) VW(3, 3, a33)
      asm volatile("s_waitcnt lgkmcnt(0)" ::: "memory");
      const int rr = lane >> 3, cc = lane & 7;
#pragma unroll
      for (int it = 0; it < 8; it++) {
        int d = it * 8 + rr;
        bf16x8 v = *(const bf16x8*)(myT + d * LTS + cc * 8);
        *(bf16x8*)(Vt + (((size_t)b * NH_ + h) * HD_ + d) * S_ + s0 + cc * 8) = v;
      }
    }
  };

  if (w < 2) epilogue();
  __syncthreads();
  if (w >= 2) epilogue();
}

// ---------------- flash attention v10 = v6 + in-register P (no LDS round-trip).
// After S^T QK^T, lane (q,t) holds P[q-row=t][kv=16s+4q+r]. cvt_pk pairs give
// 8 u32 words; A-frags use placement frag1=[s0.01,s0.23,s1.01,s1.23],
// frag2=[s2...,s3...], defining the k-permutation semantic 8q+2j+b ->
// actual kv = 16*(j>>1)+4q+2*(j&1)+b. V's B-operand reads the SAME permuted
// kv rows (two ds_read_b64 per frag per d-block), so the MFMA product is
// exact. Removes 6 DS ops + the serial LDS write->read latency per iter,
// and lP entirely: LDS 40->32KB -> 5 blocks/CU.
// Staging/sync identical to v6 (T14 reg-staged commits, lgkm-only barrier).
__global__ void __launch_bounds__(256, 4) attn_kernel(
    const bf16* __restrict__ Q, const bf16* __restrict__ K,
    const bf16* __restrict__ Vt, const float* __restrict__ mask,
    bf16* __restrict__ ctx) {
  const int b = blockIdx.y >> 4, h = blockIdx.y & 15;
  const int q0 = blockIdx.x * 64;
  __shared__ __align__(16) bf16 lK[2][64 * 64];  // lK[1] also stages Q, then O-out
  __shared__ __align__(16) bf16 lV[2][64 * 64];  // V^T tiles: [d][k]
  const int tid = threadIdx.x;
  const int lane = tid & 63, w = tid >> 6;
  const int quad = lane >> 4, l16 = lane & 15;

  // staging geometry: rows 0..31 (first half) and 32..63 (second), same row&7
  const int sr = tid >> 3;                // 0..31
  const int scs = (tid & 7) ^ (sr & 7);   // swizzled source chunk

  const size_t headoff = ((size_t)b * NH_ + h) * S_ * HD_;
  {
    const bf16* src = Q + headoff + (size_t)q0 * HD_;
    async16(src + sr * 64 + scs * 8, lK[1] + tid * 8);
    async16(src + (sr + 32) * 64 + scs * 8, lK[1] + (tid + 256) * 8);
    const bf16* ksrc = K + headoff;
    async16(ksrc + sr * 64 + scs * 8, lK[0] + tid * 8);
    async16(ksrc + (sr + 32) * 64 + scs * 8, lK[0] + (tid + 256) * 8);
    const bf16* vbase = Vt + headoff;
    async16(vbase + (size_t)sr * S_ + scs * 8, lV[0] + tid * 8);
    async16(vbase + (size_t)(sr + 32) * S_ + scs * 8, lV[0] + (tid + 256) * 8);
  }

  const float* mrow = mask + ((size_t)b * S_ + q0 + w * 16 + l16) * S_;  // lane's q-row
  const int sw = l16 & 7;
  const int pq  = (quad ^ sw) * 8;         // physical chunk offset, k-half 0
  const int pq2 = ((quad + 4) ^ sw) * 8;   // k-half 1

  // V b64 read offsets (bf16 units) for the permuted B-frags; loop-invariant.
  // logical kv chunk (q>>1)+{0,2,4,6}, physical = chunk ^ (row&7) with row=t.
  const int vo1a = (((quad >> 1) + 0) ^ sw) * 8 + (quad & 1) * 4;
  const int vo1b = (((quad >> 1) + 2) ^ sw) * 8 + (quad & 1) * 4;
  const int vo2a = (((quad >> 1) + 4) ^ sw) * 8 + (quad & 1) * 4;
  const int vo2b = (((quad >> 1) + 6) ^ sw) * 8 + (quad & 1) * 4;

  const float LOG2E = 1.44269504089f;
  const float MSH = -17.3123404907f;       // -12 * log2e (fixed shift)

  // mask tile 0 raw prefetch (transform applied at use)
  float4 g0, g1, g2, g3;
  {
    const float4* m4 = (const float4*)(mrow);
    g0 = m4[quad]; g1 = m4[4 + quad]; g2 = m4[8 + quad]; g3 = m4[12 + quad];
  }

  __syncthreads();   // Q, K0, V0 resident (one-time full drain)
  const bf16x8 qf  = *(const bf16x8*)(lK[1] + (w * 16 + l16) * 64 + pq);
  const bf16x8 qf2 = *(const bf16x8*)(lK[1] + (w * 16 + l16) * 64 + pq2);
  __syncthreads();   // all waves done reading Q; lK[1] free

  // stage tile 1 into registers (committed at iter 0's B)
  bf16x8 kr0, kr1, vr0, vr1;
  {
    const bf16* ksrc = K + headoff + (size_t)64 * HD_;
    kr0 = *(const bf16x8*)(ksrc + sr * 64 + scs * 8);
    kr1 = *(const bf16x8*)(ksrc + (sr + 32) * 64 + scs * 8);
    const bf16* vsrc = Vt + headoff + 64;
    vr0 = *(const bf16x8*)(vsrc + (size_t)sr * S_ + scs * 8);
    vr1 = *(const bf16x8*)(vsrc + (size_t)(sr + 32) * S_ + scs * 8);
  }

  f32x4 o0 = {}, o1 = {}, o2 = {}, o3 = {};
  float l_acc = 0.f;   // per-lane partial row-sum; cross-lane reduce deferred

  for (int kt = 0; kt < 32; kt++) {
    const bf16* lKc = lK[kt & 1];
    const bf16* lVc = lV[kt & 1];

    // A: QK^T. S^T form: A = K-frags (rows = kv-cols), B = Q-frag.
    f32x4 s0 = {}, s1 = {}, s2 = {}, s3 = {};
    __builtin_amdgcn_s_setprio(1);
    {
      bf16x8 k0f = *(const bf16x8*)(lKc + (0 * 16 + l16) * 64 + pq);
      bf16x8 k1f = *(const bf16x8*)(lKc + (1 * 16 + l16) * 64 + pq);
      bf16x8 k2f = *(const bf16x8*)(lKc + (2 * 16 + l16) * 64 + pq);
      bf16x8 k3f = *(const bf16x8*)(lKc + (3 * 16 + l16) * 64 + pq);
      MM16(k0f, qf, s0); MM16(k1f, qf, s1); MM16(k2f, qf, s2); MM16(k3f, qf, s3);
    }
    {
      bf16x8 k0f = *(const bf16x8*)(lKc + (0 * 16 + l16) * 64 + pq2);
      bf16x8 k1f = *(const bf16x8*)(lKc + (1 * 16 + l16) * 64 + pq2);
      bf16x8 k2f = *(const bf16x8*)(lKc + (2 * 16 + l16) * 64 + pq2);
      bf16x8 k3f = *(const bf16x8*)(lKc + (3 * 16 + l16) * 64 + pq2);
      MM16(k0f, qf2, s0); MM16(k1f, qf2, s1); MM16(k2f, qf2, s2); MM16(k3f, qf2, s3);
    }
    __builtin_amdgcn_s_setprio(0);

    // B: commit reg-staged tile kt+1 to the other buffer (precise vmcnt wait).
    if (kt < 31) {
      bf16* nK = lK[(kt & 1) ^ 1];
      bf16* nV = lV[(kt & 1) ^ 1];
      *(bf16x8*)(nK + tid * 8) = kr0;
      *(bf16x8*)(nK + (tid + 256) * 8) = kr1;
      *(bf16x8*)(nV + tid * 8) = vr0;
      *(bf16x8*)(nV + (tid + 256) * 8) = vr1;
    }

    // C: issue global->reg loads for tile kt+2 and mask kt+1 (temps).
    if (kt < 30) {
      const bf16* ksrc = K + headoff + (size_t)(kt + 2) * 64 * HD_;
      kr0 = *(const bf16x8*)(ksrc + sr * 64 + scs * 8);
      kr1 = *(const bf16x8*)(ksrc + (sr + 32) * 64 + scs * 8);
      const bf16* vsrc = Vt + headoff + (kt + 2) * 64;
      vr0 = *(const bf16x8*)(vsrc + (size_t)sr * S_ + scs * 8);
      vr1 = *(const bf16x8*)(vsrc + (size_t)(sr + 32) * S_ + scs * 8);
    }
    float4 h0, h1, h2, h3;
    if (kt < 31) {
      const float4* mn = (const float4*)(mrow + (kt + 1) * 64);
      h0 = mn[quad]; h1 = mn[4 + quad]; h2 = mn[8 + quad]; h3 = mn[12 + quad];
    }

    // D: fixed-shift softmax: P = exp2(s*log2e + (m*log2e + MSH)).
    const float fx0 = fmaf(g0.x, LOG2E, MSH), fy0 = fmaf(g0.y, LOG2E, MSH);
    const float fz0 = fmaf(g0.z, LOG2E, MSH), fw0 = fmaf(g0.w, LOG2E, MSH);
    const float fx1 = fmaf(g1.x, LOG2E, MSH), fy1 = fmaf(g1.y, LOG2E, MSH);
    const float fz1 = fmaf(g1.z, LOG2E, MSH), fw1 = fmaf(g1.w, LOG2E, MSH);
    const float fx2 = fmaf(g2.x, LOG2E, MSH), fy2 = fmaf(g2.y, LOG2E, MSH);
    const float fz2 = fmaf(g2.z, LOG2E, MSH), fw2 = fmaf(g2.w, LOG2E, MSH);
    const float fx3 = fmaf(g3.x, LOG2E, MSH), fy3 = fmaf(g3.y, LOG2E, MSH);
    const float fz3 = fmaf(g3.z, LOG2E, MSH), fw3 = fmaf(g3.w, LOG2E, MSH);
    float p00 = __builtin_amdgcn_exp2f(fmaf(s0[0], LOG2E, fx0));
    float p01 = __builtin_amdgcn_exp2f(fmaf(s0[1], LOG2E, fy0));
    float p02 = __builtin_amdgcn_exp2f(fmaf(s0[2], LOG2E, fz0));
    float p03 = __builtin_amdgcn_exp2f(fmaf(s0[3], LOG2E, fw0));
    float p10 = __builtin_amdgcn_exp2f(fmaf(s1[0], LOG2E, fx1));
    float p11 = __builtin_amdgcn_exp2f(fmaf(s1[1], LOG2E, fy1));
    float p12 = __builtin_amdgcn_exp2f(fmaf(s1[2], LOG2E, fz1));
    float p13 = __builtin_amdgcn_exp2f(fmaf(s1[3], LOG2E, fw1));
    float p20 = __builtin_amdgcn_exp2f(fmaf(s2[0], LOG2E, fx2));
    float p21 = __builtin_amdgcn_exp2f(fmaf(s2[1], LOG2E, fy2));
    float p22 = __builtin_amdgcn_exp2f(fmaf(s2[2], LOG2E, fz2));
    float p23 = __builtin_amdgcn_exp2f(fmaf(s2[3], LOG2E, fw2));
    float p30 = __builtin_amdgcn_exp2f(fmaf(s3[0], LOG2E, fx3));
    float p31 = __builtin_amdgcn_exp2f(fmaf(s3[1], LOG2E, fy3));
    float p32 = __builtin_amdgcn_exp2f(fmaf(s3[2], LOG2E, fz3));
    float p33 = __builtin_amdgcn_exp2f(fmaf(s3[3], LOG2E, fw3));

    l_acc += (((p00 + p01) + (p02 + p03)) + ((p10 + p11) + (p12 + p13)))
           + (((p20 + p21) + (p22 + p23)) + ((p30 + p31) + (p32 + p33)));

    // pack P into A-frags in-register (placement defines the k-permutation)
    union U4 { unsigned wd[4]; bf16x8 v; } f1, f2;
    f1.wd[0] = cvtpk(p00, p01); f1.wd[1] = cvtpk(p02, p03);
    f1.wd[2] = cvtpk(p10, p11); f1.wd[3] = cvtpk(p12, p13);
    f2.wd[0] = cvtpk(p20, p21); f2.wd[1] = cvtpk(p22, p23);
    f2.wd[2] = cvtpk(p30, p31); f2.wd[3] = cvtpk(p32, p33);

    // E: O += P V with permuted-k V reads (two b64 per frag per d-block).
    __builtin_amdgcn_s_setprio(1);
#define PVJ(j, oo) { \
      const bf16* vr = lVc + ((j) * 16 + l16) * 64; \
      union U4b { bf16x4 hh[2]; bf16x8 v; } b1, b2; \
      b1.hh[0] = *(const bf16x4*)(vr + vo1a); \
      b1.hh[1] = *(const bf16x4*)(vr + vo1b); \
      b2.hh[0] = *(const bf16x4*)(vr + vo2a); \
      b2.hh[1] = *(const bf16x4*)(vr + vo2b); \
      MM16(f1.v, b1.v, oo); MM16(f2.v, b2.v, oo); }
    PVJ(0, o0) PVJ(1, o1) PVJ(2, o2) PVJ(3, o3)
#undef PVJ
    __builtin_amdgcn_s_setprio(0);

    // carry mask regs for next iteration
    if (kt < 31) { g0 = h0; g1 = h1; g2 = h2; g3 = h3; }

    // F: raw barrier, NO vmem drain. lgkmcnt(0) makes my ds_writes visible
    // and my ds_reads of buf[cur] complete before anyone re-writes it.
    if (kt < 31) {
      asm volatile("s_waitcnt lgkmcnt(0)" ::: "memory");
      __builtin_amdgcn_sched_barrier(0);
      __builtin_amdgcn_s_barrier();
      __builtin_amdgcn_sched_barrier(0);
    }
  }

  // epilogue: reduce row sums, 1/l, normalize, coalesced store via lK[0]
  float l_run = l_acc;
  l_run += __shfl_xor(l_run, 16);
  l_run += __shfl_xor(l_run, 32);
  f32x4 lv;
  lv[0] = __shfl(l_run, quad * 4 + 0);
  lv[1] = __shfl(l_run, quad * 4 + 1);
  lv[2] = __shfl(l_run, quad * 4 + 2);
  lv[3] = __shfl(l_run, quad * 4 + 3);
  bf16* lO = lK[0];
#pragma unroll
  for (int r = 0; r < 4; r++) {
    const float invl = 1.0f / lv[r];
    const int sloc = w * 16 + quad * 4 + r;
    lO[sloc * 64 + l16]      = (bf16)(o0[r] * invl);
    lO[sloc * 64 + 16 + l16] = (bf16)(o1[r] * invl);
    lO[sloc * 64 + 32 + l16] = (bf16)(o2[r] * invl);
    lO[sloc * 64 + 48 + l16] = (bf16)(o3[r] * invl);
  }
  __syncthreads();
  {
    const int rr = tid >> 3, cc = tid & 7;
#pragma unroll
    for (int it = 0; it < 2; it++) {
      int sloc = it * 32 + rr;
      bf16x8 v = *(const bf16x8*)(lO + sloc * 64 + cc * 8);
      *(bf16x8*)(ctx + ((size_t)b * S_ + q0 + sloc) * HID_ + h * HD_ + cc * 8) = v;
    }
  }
}

#define PW(i, j, C) { \
  float* po = out + (size_t)(m0 + wm + (i) * 16 + quad * 4) * 1024 + n0 + wn + (j) * 16 + l16; \
  po[0] = C[0]; po[1024] = C[1]; po[2048] = C[2]; po[3072] = C[3]; }

// ---------------- output projection: out(fp32) = ctx @ Wo^T (round-9 version)
__global__ void proj_gemm(
    const bf16* __restrict__ A, const bf16* __restrict__ Wo, float* __restrict__ out) {
  const int f = blockIdx.x;
  const int orig = (f & 7) * 64 + (f >> 3);
  const int m0 = (orig >> 3) * 128;
  const int n0 = (orig & 7) * 128;
  __shared__ __align__(16) bf16 lA[128 * 32];
  __shared__ __align__(16) bf16 lB[128 * 32];
  const int tid = threadIdx.x;
  const int lane = tid & 63, w = tid >> 6;
  const int wm = (w >> 1) * 64, wn = (w & 1) * 64;
  const int quad = lane >> 4, l16 = lane & 15;

  DECL_ACC
  const int qa = tid, qb = tid + 256;
  const int ra = qa >> 2, ca = (qa & 3) * 8;
  const int rb = qb >> 2, cb = (qb & 3) * 8;

  for (int k0 = 0; k0 < 1024; k0 += 32) {
    async16(A + (size_t)(m0 + ra) * 1024 + k0 + ca, lA + qa * 8);
    async16(A + (size_t)(m0 + rb) * 1024 + k0 + cb, lA + qb * 8);
    async16(Wo + (size_t)(n0 + ra) * 1024 + k0 + ca, lB + qa * 8);
    async16(Wo + (size_t)(n0 + rb) * 1024 + k0 + cb, lB + qb * 8);
    __syncthreads();
    KLOOP_FRAGS_MFMA
    __syncthreads();
  }
  PW(0, 0, a00) PW(0, 1, a01) PW(0, 2, a02) PW(0, 3, a03)
  PW(1, 0, a10) PW(1, 1, a11) PW(1, 2, a12) PW(1, 3, a13)
  PW(2, 0, a20) PW(2, 1, a21) PW(2, 2, a22) PW(2, 3, a23)
  PW(3, 0, a30) PW(3, 1, a31) PW(3, 2, a32) PW(3, 3, a33)
}

__global__ void sentinel_kernel(float* out, int n, float val) {
  int i = blockIdx.x * 256 + threadIdx.x;
  if (i < n) out[i] = val;
}

extern "C" void kernel_launch(void* const* d_in, const int* in_sizes, int n_in,
                              void* d_out, int out_size, void* d_ws, size_t ws_size,
                              hipStream_t stream) {
  const float* X    = (const float*)d_in[0];
  const float* mask = (const float*)d_in[1];
  const int*   pos  = (const int*)d_in[2];
  const float* Wq   = (const float*)d_in[3];
  const float* Wk   = (const float*)d_in[4];
  const float* Wv   = (const float*)d_in[5];
  const float* Wo   = (const float*)d_in[6];
  float* out = (float*)d_out;

  char* ws = (char*)d_ws;
  const size_t SZ = (size_t)B_ * NH_ * S_ * HD_ * sizeof(bf16);  // 16 MiB
  if (ws_size < 3 * SZ) {
    sentinel_kernel<<<(out_size + 255) / 256, 256, 0, stream>>>(
        out, out_size, (float)(ws_size >> 20));
    return;
  }

  // ws layout (48 MiB): [0,16M) Xb then ctx; [16M,32M) Q; [32M,48M) Vt then Wob.
  bf16* Xb  = (bf16*)(ws);
  bf16* ctx = (bf16*)(ws);
  bf16* Q   = (bf16*)(ws + SZ);
  bf16* Vt  = (bf16*)(ws + 2 * SZ);
  bf16* Wob = (bf16*)(ws + 2 * SZ);
  // d_out hosts bf16 K [0,16M) and Wq/Wk/Wv bf16 [16M,22M) until proj overwrites.
  bf16* Kb  = (bf16*)d_out;
  bf16* Wqb = (bf16*)((char*)d_out + SZ);
  bf16* Wkb = Wqb + 1024 * 1024;
  bf16* Wvb = Wkb + 1024 * 1024;

  const int nX4 = (B_ * S_ * HID_) / 4;
  const int nW4 = (HID_ * HID_) / 4;
  cvt_kernel<<<(nX4 + 255) / 256, 256, 0, stream>>>(X, Xb, nX4);
  cvt_kernel<<<(nW4 + 255) / 256, 256, 0, stream>>>(Wq, Wqb, nW4);
  cvt_kernel<<<(nW4 + 255) / 256, 256, 0, stream>>>(Wk, Wkb, nW4);
  cvt_kernel<<<(nW4 + 255) / 256, 256, 0, stream>>>(Wv, Wvb, nW4);

  qkv_gemm<<<dim3(1536), 256, 0, stream>>>(Xb, Wqb, Wkb, Wvb, pos, Q, Kb, Vt);
  attn_kernel<<<dim3(32, 64), 256, 0, stream>>>(Q, Kb, Vt, mask, ctx);

  cvt_kernel<<<(nW4 + 255) / 256, 256, 0, stream>>>(Wo, Wob, nW4);
  proj_gemm<<<dim3(512), 256, 0, stream>>>(ctx, Wob, out);
}

// Round 11
// 387.606 us; speedup vs baseline: 1.0090x; 1.0090x over previous
//
#include <hip/hip_runtime.h>
#include <hip/hip_bf16.h>
#include <math.h>

typedef __bf16 bf16;
typedef bf16 bf16x4 __attribute__((ext_vector_type(4)));
typedef bf16 bf16x8 __attribute__((ext_vector_type(8)));
typedef float f32x4 __attribute__((ext_vector_type(4)));

#define B_ 4
#define S_ 2048
#define HID_ 1024
#define NH_ 16
#define HD_ 64
#define LTS 72   // padded LDS tile stride

// async global->LDS, 16B per lane. LDS dest must be wave-uniform base + lane*16.
__device__ __forceinline__ void async16(const bf16* g, bf16* l) {
  __builtin_amdgcn_global_load_lds(
      (const __attribute__((address_space(1))) void*)g,
      (__attribute__((address_space(3))) void*)l, 16, 0, 0);
}

#define MM16(A, B, C) C = __builtin_amdgcn_mfma_f32_16x16x32_bf16(A, B, C, 0, 0, 0)

// pack two f32 -> u32 of 2 bf16 (no builtin on gfx950; T12 recipe)
__device__ __forceinline__ unsigned cvtpk(float lo, float hi) {
  unsigned r;
  asm("v_cvt_pk_bf16_f32 %0, %1, %2" : "=v"(r) : "v"(lo), "v"(hi));
  return r;
}

// ---------------- fp32 -> bf16 convert
__global__ void cvt_kernel(const float* __restrict__ src, bf16* __restrict__ dst, int n4) {
  int i = blockIdx.x * 256 + threadIdx.x;
  if (i < n4) {
    float4 v = ((const float4*)src)[i];
    bf16x4 o;
    o[0] = (bf16)v.x; o[1] = (bf16)v.y; o[2] = (bf16)v.z; o[3] = (bf16)v.w;
    ((bf16x4*)dst)[i] = o;
  }
}

// K-loop body shared by qkv/proj: named accs, frag loads, 16 MFMAs.
#define DECL_ACC \
  f32x4 a00 = {}, a01 = {}, a02 = {}, a03 = {}; \
  f32x4 a10 = {}, a11 = {}, a12 = {}, a13 = {}; \
  f32x4 a20 = {}, a21 = {}, a22 = {}, a23 = {}; \
  f32x4 a30 = {}, a31 = {}, a32 = {}, a33 = {};

#define KLOOP_FRAGS_MFMA \
    bf16x8 af0 = *(const bf16x8*)(lA + (wm + 0 * 16 + l16) * 32 + quad * 8); \
    bf16x8 af1 = *(const bf16x8*)(lA + (wm + 1 * 16 + l16) * 32 + quad * 8); \
    bf16x8 af2 = *(const bf16x8*)(lA + (wm + 2 * 16 + l16) * 32 + quad * 8); \
    bf16x8 af3 = *(const bf16x8*)(lA + (wm + 3 * 16 + l16) * 32 + quad * 8); \
    bf16x8 bg0 = *(const bf16x8*)(lB + (wn + 0 * 16 + l16) * 32 + quad * 8); \
    bf16x8 bg1 = *(const bf16x8*)(lB + (wn + 1 * 16 + l16) * 32 + quad * 8); \
    bf16x8 bg2 = *(const bf16x8*)(lB + (wn + 2 * 16 + l16) * 32 + quad * 8); \
    bf16x8 bg3 = *(const bf16x8*)(lB + (wn + 3 * 16 + l16) * 32 + quad * 8); \
    MM16(af0, bg0, a00); MM16(af0, bg1, a01); MM16(af0, bg2, a02); MM16(af0, bg3, a03); \
    MM16(af1, bg0, a10); MM16(af1, bg1, a11); MM16(af1, bg2, a12); MM16(af1, bg3, a13); \
    MM16(af2, bg0, a20); MM16(af2, bg1, a21); MM16(af2, bg2, a22); MM16(af2, bg3, a23); \
    MM16(af3, bg0, a30); MM16(af3, bg1, a31); MM16(af3, bg2, a32); MM16(af3, bg3, a33);

// RoPE epilogue per (i, r) — fast trig (range ~2048 rad: __cosf err ~1e-4 << bf16 eps)
#define ROPE_R(i, r, C0, C1, C2, C3) { \
  const int mloc = (i) * 16 + quad * 4 + (r); \
  const float p = (float)pos[mbase + mloc]; \
  const float aa0 = p * invf0, aa1 = p * invf1; \
  const float c0 = __cosf(aa0), sn0 = __sinf(aa0); \
  const float c1 = __cosf(aa1), sn1 = __sinf(aa1); \
  myT[mloc * LTS + l16]      = (bf16)((C0[r] * c0 - C2[r] * sn0) * scl); \
  myT[mloc * LTS + 32 + l16] = (bf16)((C2[r] * c0 + C0[r] * sn0) * scl); \
  myT[mloc * LTS + 16 + l16] = (bf16)((C1[r] * c1 - C3[r] * sn1) * scl); \
  myT[mloc * LTS + 48 + l16] = (bf16)((C3[r] * c1 + C1[r] * sn1) * scl); }
#define ROPE_I(i, C0, C1, C2, C3) \
  ROPE_R(i, 0, C0, C1, C2, C3) ROPE_R(i, 1, C0, C1, C2, C3) \
  ROPE_R(i, 2, C0, C1, C2, C3) ROPE_R(i, 3, C0, C1, C2, C3)

#define VW(i, j, C) { \
  bf16x4 o; o[0] = (bf16)C[0]; o[1] = (bf16)C[1]; o[2] = (bf16)C[2]; o[3] = (bf16)C[3]; \
  *(bf16x4*)(myT + ((j) * 16 + l16) * LTS + (i) * 16 + quad * 4) = o; }

// ---------------- QKV GEMM: Y = Xb @ Wb^T, fused RoPE. (round-9 version)
__global__ void qkv_gemm(
    const bf16* __restrict__ X, const bf16* __restrict__ Wq,
    const bf16* __restrict__ Wk, const bf16* __restrict__ Wv,
    const int* __restrict__ pos,
    bf16* __restrict__ Q, bf16* __restrict__ Ko, bf16* __restrict__ Vt) {
  const int f = blockIdx.x;
  const int orig = (f & 7) * 192 + (f >> 3);
  const int m_idx = orig / 24, nz = orig % 24;
  const int z = nz % 3;
  const bf16* W = (z == 0) ? Wq : (z == 1) ? Wk : Wv;
  const int m0 = m_idx * 128;
  const int n0 = (nz / 3) * 128;
  __shared__ __align__(16) bf16 lA[128 * 32];
  __shared__ __align__(16) bf16 lB[128 * 32];
  __shared__ __align__(16) bf16 lT[2][64 * LTS];  // 2-phase epilogue buffer
  const int tid = threadIdx.x;
  const int lane = tid & 63, w = tid >> 6;
  const int wm = (w >> 1) * 64, wn = (w & 1) * 64;
  const int quad = lane >> 4, l16 = lane & 15;

  DECL_ACC

  const int qa = tid, qb = tid + 256;
  const int ra = qa >> 2, ca = (qa & 3) * 8;
  const int rb = qb >> 2, cb = (qb & 3) * 8;

  for (int k0 = 0; k0 < 1024; k0 += 32) {
    async16(X + (size_t)(m0 + ra) * 1024 + k0 + ca, lA + qa * 8);
    async16(X + (size_t)(m0 + rb) * 1024 + k0 + cb, lA + qb * 8);
    async16(W + (size_t)(n0 + ra) * 1024 + k0 + ca, lB + qa * 8);
    async16(W + (size_t)(n0 + rb) * 1024 + k0 + cb, lB + qb * 8);
    __syncthreads();
    KLOOP_FRAGS_MFMA
    __syncthreads();
  }

  const int h = (n0 + wn) >> 6;
  const int mbase = m0 + wm;
  const int b = mbase >> 11, s0 = mbase & 2047;
  bf16* myT = lT[w & 1];

  auto epilogue = [&]() {
    if (z <= 1) {
      const float scl = (z == 0) ? 0.125f : 1.0f;
      const float invf0 = __expf(-0.28782313662425572f * (float)l16);   // ln(1e4)/32
      const float invf1 = __expf(-0.28782313662425572f * (float)(16 + l16));
      ROPE_I(0, a00, a01, a02, a03)
      ROPE_I(1, a10, a11, a12, a13)
      ROPE_I(2, a20, a21, a22, a23)
      ROPE_I(3, a30, a31, a32, a33)
      asm volatile("s_waitcnt lgkmcnt(0)" ::: "memory");
      bf16* dst = (z == 0) ? Q : Ko;
      const int rr = lane >> 3, cc = lane & 7;
#pragma unroll
      for (int it = 0; it < 8; it++) {
        int mloc = it * 8 + rr;
        bf16x8 v = *(const bf16x8*)(myT + mloc * LTS + cc * 8);
        *(bf16x8*)(dst + (((size_t)b * NH_ + h) * S_ + s0 + mloc) * HD_ + cc * 8) = v;
      }
    } else {
      VW(0, 0, a00) VW(0, 1, a01) VW(0, 2, a02) VW(0, 3, a03)
      VW(1, 0, a10) VW(1, 1, a11) VW(1, 2, a12) VW(1, 3, a13)
      VW(2, 0, a20) VW(2, 1, a21) VW(2, 2, a22) VW(2, 3, a23)
      VW(3, 0, a30) VW(3, 1, a31) VW(3, 2, a32) VW(3, 3, a33)
      asm volatile("s_waitcnt lgkmcnt(0)" ::: "memory");
      const int rr = lane >> 3, cc = lane & 7;
#pragma unroll
      for (int it = 0; it < 8; it++) {
        int d = it * 8 + rr;
        bf16x8 v = *(const bf16x8*)(myT + d * LTS + cc * 8);
        *(bf16x8*)(Vt + (((size_t)b * NH_ + h) * HD_ + d) * S_ + s0 + cc * 8) = v;
      }
    }
  };

  if (w < 2) epilogue();
  __syncthreads();
  if (w >= 2) epilogue();
}

// ---------------- flash attention v11 = v6 + in-register P + sigma-transposed
// V LDS layout. A-frag placement (harness-verified in v10): f1=[s0.01,s0.23,
// s1.01,s1.23], f2=[s2..,s3..] -> semantic k=8q+2w+b maps to actual
// kv=16*(w>>1)+4q+2*(w&1)+b. V LDS stores position-nibble t=4a+b <- kv-nibble
// 4b+a (involution), so lane q's frag1 kv set {4q..4q+3,16+4q..19+4q} is the
// CONTIGUOUS position chunk 2q (one b128, order verified element-wise) and
// frag2 is chunk 2q+1. Bank swizzle: physchunk = poschunk ^ (row&7) -> same
// 2-way-free pattern as v6. V is committed by per-nibble ds_write_b64 (layout
// is free on the T14 reg-commit path); V0 is reg-staged in the prologue
// (+1 prologue barrier). P never touches LDS; lP deleted -> LDS 32KB.
__global__ void __launch_bounds__(256, 4) attn_kernel(
    const bf16* __restrict__ Q, const bf16* __restrict__ K,
    const bf16* __restrict__ Vt, const float* __restrict__ mask,
    bf16* __restrict__ ctx) {
  const int b = blockIdx.y >> 4, h = blockIdx.y & 15;
  const int q0 = blockIdx.x * 64;
  __shared__ __align__(16) bf16 lK[2][64 * 64];  // lK[1] also stages Q, then O-out
  __shared__ __align__(16) bf16 lV[2][64 * 64];  // V^T tiles, sigma-transposed cols
  const int tid = threadIdx.x;
  const int lane = tid & 63, w = tid >> 6;
  const int quad = lane >> 4, l16 = lane & 15;

  // staging geometry: rows 0..31 (first half) and 32..63 (second), same row&7
  const int sr = tid >> 3;                // 0..31
  const int scs = (tid & 7) ^ (sr & 7);   // swizzled source chunk (K/Q only)
  const int m = tid & 7;                  // plain source chunk (V)
  // V commit nibbles: source chunk m holds kv nibbles 2m,2m+1 -> positions
  // t0 = sigma(2m) = 8*(m&1)+(m>>1), t1 = t0+4.
  const int t0 = 8 * (m & 1) + (m >> 1);
  const int t1 = t0 + 4;
  const int srk = sr & 7;
  const int vwo0 = ((t0 >> 1) ^ srk) * 8 + (t0 & 1) * 4;  // bf16 offset in row
  const int vwo1 = ((t1 >> 1) ^ srk) * 8 + (t1 & 1) * 4;

#define VCOMMIT(dstbuf, va, vb) { \
    union { bf16x4 hh[2]; bf16x8 v8; } uA_, uB_; \
    uA_.v8 = (va); uB_.v8 = (vb); \
    bf16* pa_ = (dstbuf) + sr * 64; \
    bf16* pb_ = (dstbuf) + (sr + 32) * 64; \
    *(bf16x4*)(pa_ + vwo0) = uA_.hh[0]; \
    *(bf16x4*)(pa_ + vwo1) = uA_.hh[1]; \
    *(bf16x4*)(pb_ + vwo0) = uB_.hh[0]; \
    *(bf16x4*)(pb_ + vwo1) = uB_.hh[1]; }

  const size_t headoff = ((size_t)b * NH_ + h) * S_ * HD_;
  {
    const bf16* src = Q + headoff + (size_t)q0 * HD_;
    async16(src + sr * 64 + scs * 8, lK[1] + tid * 8);
    async16(src + (sr + 32) * 64 + scs * 8, lK[1] + (tid + 256) * 8);
    const bf16* ksrc = K + headoff;
    async16(ksrc + sr * 64 + scs * 8, lK[0] + tid * 8);
    async16(ksrc + (sr + 32) * 64 + scs * 8, lK[0] + (tid + 256) * 8);
  }
  // V0 to regs (plain source chunks; committed after Q frags are hoisted)
  bf16x8 vv0, vv1;
  {
    const bf16* vsrc = Vt + headoff;
    vv0 = *(const bf16x8*)(vsrc + (size_t)sr * S_ + m * 8);
    vv1 = *(const bf16x8*)(vsrc + (size_t)(sr + 32) * S_ + m * 8);
  }

  const float* mrow = mask + ((size_t)b * S_ + q0 + w * 16 + l16) * S_;  // lane's q-row
  const int sw = l16 & 7;
  const int pq  = (quad ^ sw) * 8;         // physical chunk offset, k-half 0 (K/Q)
  const int pq2 = ((quad + 4) ^ sw) * 8;   // k-half 1

  const float LOG2E = 1.44269504089f;
  const float MSH = -17.3123404907f;       // -12 * log2e (fixed shift)

  // mask tile 0 raw prefetch (transform applied at use)
  float4 g0, g1, g2, g3;
  {
    const float4* m4 = (const float4*)(mrow);
    g0 = m4[quad]; g1 = m4[4 + quad]; g2 = m4[8 + quad]; g3 = m4[12 + quad];
  }

  __syncthreads();   // Q, K0 resident (full drain)
  const bf16x8 qf  = *(const bf16x8*)(lK[1] + (w * 16 + l16) * 64 + pq);
  const bf16x8 qf2 = *(const bf16x8*)(lK[1] + (w * 16 + l16) * 64 + pq2);
  __syncthreads();   // all waves done reading Q; lK[1] free

  // commit V0 (sigma layout), stage tile 1 into registers
  VCOMMIT(lV[0], vv0, vv1);
  bf16x8 kr0, kr1, vr0, vr1;
  {
    const bf16* ksrc = K + headoff + (size_t)64 * HD_;
    kr0 = *(const bf16x8*)(ksrc + sr * 64 + scs * 8);
    kr1 = *(const bf16x8*)(ksrc + (sr + 32) * 64 + scs * 8);
    const bf16* vsrc = Vt + headoff + 64;
    vr0 = *(const bf16x8*)(vsrc + (size_t)sr * S_ + m * 8);
    vr1 = *(const bf16x8*)(vsrc + (size_t)(sr + 32) * S_ + m * 8);
  }
  asm volatile("s_waitcnt lgkmcnt(0)" ::: "memory");
  __builtin_amdgcn_sched_barrier(0);
  __builtin_amdgcn_s_barrier();   // V0 visible to all waves
  __builtin_amdgcn_sched_barrier(0);

  f32x4 o0 = {}, o1 = {}, o2 = {}, o3 = {};
  float l_acc = 0.f;   // per-lane partial row-sum; cross-lane reduce deferred

  for (int kt = 0; kt < 32; kt++) {
    const bf16* lKc = lK[kt & 1];
    const bf16* lVc = lV[kt & 1];

    // A: QK^T. S^T form: A = K-frags (rows = kv-cols), B = Q-frag.
    f32x4 s0 = {}, s1 = {}, s2 = {}, s3 = {};
    __builtin_amdgcn_s_setprio(1);
    {
      bf16x8 k0f = *(const bf16x8*)(lKc + (0 * 16 + l16) * 64 + pq);
      bf16x8 k1f = *(const bf16x8*)(lKc + (1 * 16 + l16) * 64 + pq);
      bf16x8 k2f = *(const bf16x8*)(lKc + (2 * 16 + l16) * 64 + pq);
      bf16x8 k3f = *(const bf16x8*)(lKc + (3 * 16 + l16) * 64 + pq);
      MM16(k0f, qf, s0); MM16(k1f, qf, s1); MM16(k2f, qf, s2); MM16(k3f, qf, s3);
    }
    {
      bf16x8 k0f = *(const bf16x8*)(lKc + (0 * 16 + l16) * 64 + pq2);
      bf16x8 k1f = *(const bf16x8*)(lKc + (1 * 16 + l16) * 64 + pq2);
      bf16x8 k2f = *(const bf16x8*)(lKc + (2 * 16 + l16) * 64 + pq2);
      bf16x8 k3f = *(const bf16x8*)(lKc + (3 * 16 + l16) * 64 + pq2);
      MM16(k0f, qf2, s0); MM16(k1f, qf2, s1); MM16(k2f, qf2, s2); MM16(k3f, qf2, s3);
    }
    __builtin_amdgcn_s_setprio(0);

    // B: commit reg-staged tile kt+1 (K linear+src-swizzled, V sigma layout).
    if (kt < 31) {
      bf16* nK = lK[(kt & 1) ^ 1];
      bf16* nV = lV[(kt & 1) ^ 1];
      *(bf16x8*)(nK + tid * 8) = kr0;
      *(bf16x8*)(nK + (tid + 256) * 8) = kr1;
      VCOMMIT(nV, vr0, vr1);
    }

    // C: issue global->reg loads for tile kt+2 and mask kt+1 (temps).
    if (kt < 30) {
      const bf16* ksrc = K + headoff + (size_t)(kt + 2) * 64 * HD_;
      kr0 = *(const bf16x8*)(ksrc + sr * 64 + scs * 8);
      kr1 = *(const bf16x8*)(ksrc + (sr + 32) * 64 + scs * 8);
      const bf16* vsrc = Vt + headoff + (kt + 2) * 64;
      vr0 = *(const bf16x8*)(vsrc + (size_t)sr * S_ + m * 8);
      vr1 = *(const bf16x8*)(vsrc + (size_t)(sr + 32) * S_ + m * 8);
    }
    float4 h0, h1, h2, h3;
    if (kt < 31) {
      const float4* mn = (const float4*)(mrow + (kt + 1) * 64);
      h0 = mn[quad]; h1 = mn[4 + quad]; h2 = mn[8 + quad]; h3 = mn[12 + quad];
    }

    // D: fixed-shift softmax: P = exp2(s*log2e + (m*log2e + MSH)).
    const float fx0 = fmaf(g0.x, LOG2E, MSH), fy0 = fmaf(g0.y, LOG2E, MSH);
    const float fz0 = fmaf(g0.z, LOG2E, MSH), fw0 = fmaf(g0.w, LOG2E, MSH);
    const float fx1 = fmaf(g1.x, LOG2E, MSH), fy1 = fmaf(g1.y, LOG2E, MSH);
    const float fz1 = fmaf(g1.z, LOG2E, MSH), fw1 = fmaf(g1.w, LOG2E, MSH);
    const float fx2 = fmaf(g2.x, LOG2E, MSH), fy2 = fmaf(g2.y, LOG2E, MSH);
    const float fz2 = fmaf(g2.z, LOG2E, MSH), fw2 = fmaf(g2.w, LOG2E, MSH);
    const float fx3 = fmaf(g3.x, LOG2E, MSH), fy3 = fmaf(g3.y, LOG2E, MSH);
    const float fz3 = fmaf(g3.z, LOG2E, MSH), fw3 = fmaf(g3.w, LOG2E, MSH);
    float p00 = __builtin_amdgcn_exp2f(fmaf(s0[0], LOG2E, fx0));
    float p01 = __builtin_amdgcn_exp2f(fmaf(s0[1], LOG2E, fy0));
    float p02 = __builtin_amdgcn_exp2f(fmaf(s0[2], LOG2E, fz0));
    float p03 = __builtin_amdgcn_exp2f(fmaf(s0[3], LOG2E, fw0));
    float p10 = __builtin_amdgcn_exp2f(fmaf(s1[0], LOG2E, fx1));
    float p11 = __builtin_amdgcn_exp2f(fmaf(s1[1], LOG2E, fy1));
    float p12 = __builtin_amdgcn_exp2f(fmaf(s1[2], LOG2E, fz1));
    float p13 = __builtin_amdgcn_exp2f(fmaf(s1[3], LOG2E, fw1));
    float p20 = __builtin_amdgcn_exp2f(fmaf(s2[0], LOG2E, fx2));
    float p21 = __builtin_amdgcn_exp2f(fmaf(s2[1], LOG2E, fy2));
    float p22 = __builtin_amdgcn_exp2f(fmaf(s2[2], LOG2E, fz2));
    float p23 = __builtin_amdgcn_exp2f(fmaf(s2[3], LOG2E, fw2));
    float p30 = __builtin_amdgcn_exp2f(fmaf(s3[0], LOG2E, fx3));
    float p31 = __builtin_amdgcn_exp2f(fmaf(s3[1], LOG2E, fy3));
    float p32 = __builtin_amdgcn_exp2f(fmaf(s3[2], LOG2E, fz3));
    float p33 = __builtin_amdgcn_exp2f(fmaf(s3[3], LOG2E, fw3));

    l_acc += (((p00 + p01) + (p02 + p03)) + ((p10 + p11) + (p12 + p13)))
           + (((p20 + p21) + (p22 + p23)) + ((p30 + p31) + (p32 + p33)));

    // pack P into A-frags in-register (placement defines the k-permutation)
    union U4 { unsigned wd[4]; bf16x8 v; } f1, f2;
    f1.wd[0] = cvtpk(p00, p01); f1.wd[1] = cvtpk(p02, p03);
    f1.wd[2] = cvtpk(p10, p11); f1.wd[3] = cvtpk(p12, p13);
    f2.wd[0] = cvtpk(p20, p21); f2.wd[1] = cvtpk(p22, p23);
    f2.wd[2] = cvtpk(p30, p31); f2.wd[3] = cvtpk(p32, p33);

    // E: O += P V. Sigma layout makes the permuted B-frags contiguous b128:
    // frag1 = position chunk 2q, frag2 = chunk 2q+1 (bank-swizzled by row).
    __builtin_amdgcn_s_setprio(1);
#define PVJ(j, oo) { \
      const bf16* vr_ = lVc + ((j) * 16 + l16) * 64; \
      bf16x8 b1 = *(const bf16x8*)(vr_ + ((2 * quad) ^ sw) * 8); \
      bf16x8 b2 = *(const bf16x8*)(vr_ + ((2 * quad + 1) ^ sw) * 8); \
      MM16(f1.v, b1, oo); MM16(f2.v, b2, oo); }
    PVJ(0, o0) PVJ(1, o1) PVJ(2, o2) PVJ(3, o3)
#undef PVJ
    __builtin_amdgcn_s_setprio(0);

    // carry mask regs for next iteration
    if (kt < 31) { g0 = h0; g1 = h1; g2 = h2; g3 = h3; }

    // F: raw barrier, NO vmem drain. lgkmcnt(0) makes my ds_writes visible
    // and my ds_reads of buf[cur] complete before anyone re-writes it.
    if (kt < 31) {
      asm volatile("s_waitcnt lgkmcnt(0)" ::: "memory");
      __builtin_amdgcn_sched_barrier(0);
      __builtin_amdgcn_s_barrier();
      __builtin_amdgcn_sched_barrier(0);
    }
  }

  // epilogue: reduce row sums, 1/l, normalize, coalesced store via lK[0]
  float l_run = l_acc;
  l_run += __shfl_xor(l_run, 16);
  l_run += __shfl_xor(l_run, 32);
  f32x4 lv;
  lv[0] = __shfl(l_run, quad * 4 + 0);
  lv[1] = __shfl(l_run, quad * 4 + 1);
  lv[2] = __shfl(l_run, quad * 4 + 2);
  lv[3] = __shfl(l_run, quad * 4 + 3);
  bf16* lO = lK[0];
#pragma unroll
  for (int r = 0; r < 4; r++) {
    const float invl = 1.0f / lv[r];
    const int sloc = w * 16 + quad * 4 + r;
    lO[sloc * 64 + l16]      = (bf16)(o0[r] * invl);
    lO[sloc * 64 + 16 + l16] = (bf16)(o1[r] * invl);
    lO[sloc * 64 + 32 + l16] = (bf16)(o2[r] * invl);
    lO[sloc * 64 + 48 + l16] = (bf16)(o3[r] * invl);
  }
  __syncthreads();
  {
    const int rr = tid >> 3, cc = tid & 7;
#pragma unroll
    for (int it = 0; it < 2; it++) {
      int sloc = it * 32 + rr;
      bf16x8 v = *(const bf16x8*)(lO + sloc * 64 + cc * 8);
      *(bf16x8*)(ctx + ((size_t)b * S_ + q0 + sloc) * HID_ + h * HD_ + cc * 8) = v;
    }
  }
#undef VCOMMIT
}

#define PW(i, j, C) { \
  float* po = out + (size_t)(m0 + wm + (i) * 16 + quad * 4) * 1024 + n0 + wn + (j) * 16 + l16; \
  po[0] = C[0]; po[1024] = C[1]; po[2048] = C[2]; po[3072] = C[3]; }

// ---------------- output projection: out(fp32) = ctx @ Wo^T (round-9 version)
__global__ void proj_gemm(
    const bf16* __restrict__ A, const bf16* __restrict__ Wo, float* __restrict__ out) {
  const int f = blockIdx.x;
  const int orig = (f & 7) * 64 + (f >> 3);
  const int m0 = (orig >> 3) * 128;
  const int n0 = (orig & 7) * 128;
  __shared__ __align__(16) bf16 lA[128 * 32];
  __shared__ __align__(16) bf16 lB[128 * 32];
  const int tid = threadIdx.x;
  const int lane = tid & 63, w = tid >> 6;
  const int wm = (w >> 1) * 64, wn = (w & 1) * 64;
  const int quad = lane >> 4, l16 = lane & 15;

  DECL_ACC
  const int qa = tid, qb = tid + 256;
  const int ra = qa >> 2, ca = (qa & 3) * 8;
  const int rb = qb >> 2, cb = (qb & 3) * 8;

  for (int k0 = 0; k0 < 1024; k0 += 32) {
    async16(A + (size_t)(m0 + ra) * 1024 + k0 + ca, lA + qa * 8);
    async16(A + (size_t)(m0 + rb) * 1024 + k0 + cb, lA + qb * 8);
    async16(Wo + (size_t)(n0 + ra) * 1024 + k0 + ca, lB + qa * 8);
    async16(Wo + (size_t)(n0 + rb) * 1024 + k0 + cb, lB + qb * 8);
    __syncthreads();
    KLOOP_FRAGS_MFMA
    __syncthreads();
  }
  PW(0, 0, a00) PW(0, 1, a01) PW(0, 2, a02) PW(0, 3, a03)
  PW(1, 0, a10) PW(1, 1, a11) PW(1, 2, a12) PW(1, 3, a13)
  PW(2, 0, a20) PW(2, 1, a21) PW(2, 2, a22) PW(2, 3, a23)
  PW(3, 0, a30) PW(3, 1, a31) PW(3, 2, a32) PW(3, 3, a33)
}

__global__ void sentinel_kernel(float* out, int n, float val) {
  int i = blockIdx.x * 256 + threadIdx.x;
  if (i < n) out[i] = val;
}

extern "C" void kernel_launch(void* const* d_in, const int* in_sizes, int n_in,
                              void* d_out, int out_size, void* d_ws, size_t ws_size,
                              hipStream_t stream) {
  const float* X    = (const float*)d_in[0];
  const float* mask = (const float*)d_in[1];
  const int*   pos  = (const int*)d_in[2];
  const float* Wq   = (const float*)d_in[3];
  const float* Wk   = (const float*)d_in[4];
  const float* Wv   = (const float*)d_in[5];
  const float* Wo   = (const float*)d_in[6];
  float* out = (float*)d_out;

  char* ws = (char*)d_ws;
  const size_t SZ = (size_t)B_ * NH_ * S_ * HD_ * sizeof(bf16);  // 16 MiB
  if (ws_size < 3 * SZ) {
    sentinel_kernel<<<(out_size + 255) / 256, 256, 0, stream>>>(
        out, out_size, (float)(ws_size >> 20));
    return;
  }

  // ws layout (48 MiB): [0,16M) Xb then ctx; [16M,32M) Q; [32M,48M) Vt then Wob.
  bf16* Xb  = (bf16*)(ws);
  bf16* ctx = (bf16*)(ws);
  bf16* Q   = (bf16*)(ws + SZ);
  bf16* Vt  = (bf16*)(ws + 2 * SZ);
  bf16* Wob = (bf16*)(ws + 2 * SZ);
  // d_out hosts bf16 K [0,16M) and Wq/Wk/Wv bf16 [16M,22M) until proj overwrites.
  bf16* Kb  = (bf16*)d_out;
  bf16* Wqb = (bf16*)((char*)d_out + SZ);
  bf16* Wkb = Wqb + 1024 * 1024;
  bf16* Wvb = Wkb + 1024 * 1024;

  const int nX4 = (B_ * S_ * HID_) / 4;
  const int nW4 = (HID_ * HID_) / 4;
  cvt_kernel<<<(nX4 + 255) / 256, 256, 0, stream>>>(X, Xb, nX4);
  cvt_kernel<<<(nW4 + 255) / 256, 256, 0, stream>>>(Wq, Wqb, nW4);
  cvt_kernel<<<(nW4 + 255) / 256, 256, 0, stream>>>(Wk, Wkb, nW4);
  cvt_kernel<<<(nW4 + 255) / 256, 256, 0, stream>>>(Wv, Wvb, nW4);

  qkv_gemm<<<dim3(1536), 256, 0, stream>>>(Xb, Wqb, Wkb, Wvb, pos, Q, Kb, Vt);
  attn_kernel<<<dim3(32, 64), 256, 0, stream>>>(Q, Kb, Vt, mask, ctx);

  cvt_kernel<<<(nW4 + 255) / 256, 256, 0, stream>>>(Wo, Wob, nW4);
  proj_gemm<<<dim3(512), 256, 0, stream>>>(ctx, Wob, out);
}